// Round 1
// baseline (339.883 us; speedup 1.0000x reference)
//
#include <hip/hip_runtime.h>
#include <hip/hip_bf16.h>

#define NB 1024
#define ND 512
#define NM 65536
#define NC 4096
#define RPB 16

static constexpr float TEMP = 0.05f;
static constexpr float EPSF = 1e-6f;

// ---------- K1: row L2-normalize inputs (one 128-thread block per row) ----------
__global__ __launch_bounds__(128) void k_normalize(const float* __restrict__ in,
                                                   float* __restrict__ xn) {
    int b = blockIdx.x;
    const float4* row = reinterpret_cast<const float4*>(in + (size_t)b * ND);
    float4 v = row[threadIdx.x];
    float ss = v.x * v.x + v.y * v.y + v.z * v.z + v.w * v.w;
#pragma unroll
    for (int o = 32; o > 0; o >>= 1) ss += __shfl_down(ss, o);
    __shared__ float sw[2];
    int lane = threadIdx.x & 63, w = threadIdx.x >> 6;
    if (lane == 0) sw[w] = ss;
    __syncthreads();
    float inv = 1.0f / sqrtf(sw[0] + sw[1]);
    v.x *= inv; v.y *= inv; v.z *= inv; v.w *= inv;
    reinterpret_cast<float4*>(xn + (size_t)b * ND)[threadIdx.x] = v;
}

// ---------- K2: per-cluster member counts ----------
__global__ __launch_bounds__(256) void k_count(const int* __restrict__ labels,
                                               int* __restrict__ counts) {
    int m = blockIdx.x * 256 + threadIdx.x;
    if (m < NM) atomicAdd(&counts[labels[m]], 1);
}

// ---------- K3: scatter-add features into cluster centroids G[C][D] ----------
__global__ __launch_bounds__(256) void k_centroid(const float* __restrict__ feats,
                                                  const int* __restrict__ labels,
                                                  float* __restrict__ G) {
    int m0 = blockIdx.x * RPB;
    int t = threadIdx.x;
    for (int r = 0; r < RPB; ++r) {
        int m = m0 + r;
        int c = labels[m];
        float2 v = reinterpret_cast<const float2*>(feats + (size_t)m * ND)[t];
        float* g = G + (size_t)c * ND + 2 * t;
        atomicAdd(g, v.x);
        atomicAdd(g + 1, v.y);
    }
}

// ---------- K4: avg[b][c] = (xn[b] . G[c]) / (TEMP * max(nums[c],1)) ----------
// Tiled f32 GEMM: 64x64 tile per block, 256 threads, 4x4 micro-tile, BK=16.
__global__ __launch_bounds__(256) void k_gemm(const float* __restrict__ A,
                                              const float* __restrict__ Bm,
                                              const int* __restrict__ counts,
                                              float* __restrict__ out) {
    __shared__ float As[16][65];
    __shared__ float Bs[16][65];
    const int bm = blockIdx.y * 64;  // over B (rows)
    const int bn = blockIdx.x * 64;  // over C (cols)
    const int tid = threadIdx.x;
    const int tx = tid & 15, ty = tid >> 4;
    const int lr = tid >> 2;          // 0..63 tile row to load
    const int lk = (tid & 3) << 2;    // 0,4,8,12 k offset
    float acc[4][4] = {};
    const float* Aptr = A + (size_t)(bm + lr) * ND + lk;
    const float* Bptr = Bm + (size_t)(bn + lr) * ND + lk;
    for (int k0 = 0; k0 < ND; k0 += 16) {
        float4 av = *reinterpret_cast<const float4*>(Aptr + k0);
        float4 bv = *reinterpret_cast<const float4*>(Bptr + k0);
        As[lk + 0][lr] = av.x; As[lk + 1][lr] = av.y;
        As[lk + 2][lr] = av.z; As[lk + 3][lr] = av.w;
        Bs[lk + 0][lr] = bv.x; Bs[lk + 1][lr] = bv.y;
        Bs[lk + 2][lr] = bv.z; Bs[lk + 3][lr] = bv.w;
        __syncthreads();
#pragma unroll
        for (int k = 0; k < 16; ++k) {
            float a0 = As[k][ty * 4 + 0], a1 = As[k][ty * 4 + 1];
            float a2 = As[k][ty * 4 + 2], a3 = As[k][ty * 4 + 3];
            float b0 = Bs[k][tx * 4 + 0], b1 = Bs[k][tx * 4 + 1];
            float b2 = Bs[k][tx * 4 + 2], b3 = Bs[k][tx * 4 + 3];
            acc[0][0] += a0 * b0; acc[0][1] += a0 * b1; acc[0][2] += a0 * b2; acc[0][3] += a0 * b3;
            acc[1][0] += a1 * b0; acc[1][1] += a1 * b1; acc[1][2] += a1 * b2; acc[1][3] += a1 * b3;
            acc[2][0] += a2 * b0; acc[2][1] += a2 * b1; acc[2][2] += a2 * b2; acc[2][3] += a2 * b3;
            acc[3][0] += a3 * b0; acc[3][1] += a3 * b1; acc[3][2] += a3 * b2; acc[3][3] += a3 * b3;
        }
        __syncthreads();
    }
    int c0 = bn + tx * 4;
    float i0 = 1.0f / (TEMP * (float)(counts[c0 + 0] > 0 ? counts[c0 + 0] : 1));
    float i1 = 1.0f / (TEMP * (float)(counts[c0 + 1] > 0 ? counts[c0 + 1] : 1));
    float i2 = 1.0f / (TEMP * (float)(counts[c0 + 2] > 0 ? counts[c0 + 2] : 1));
    float i3 = 1.0f / (TEMP * (float)(counts[c0 + 3] > 0 ? counts[c0 + 3] : 1));
#pragma unroll
    for (int i = 0; i < 4; ++i) {
        int rowb = bm + ty * 4 + i;
        float4 o;
        o.x = acc[i][0] * i0; o.y = acc[i][1] * i1;
        o.z = acc[i][2] * i2; o.w = acc[i][3] * i3;
        *reinterpret_cast<float4*>(out + (size_t)rowb * NC + c0) = o;
    }
}

// ---------- K5: per-sample masked softmax + NLL ----------
__global__ __launch_bounds__(256) void k_loss(const float* __restrict__ avg,
                                              const int* __restrict__ counts,
                                              const int* __restrict__ indexes,
                                              const int* __restrict__ labels,
                                              float* __restrict__ loss_b) {
    int b = blockIdx.x;
    const float* row = avg + (size_t)b * NC;
    float s = 0.f;
    for (int c = threadIdx.x; c < NC; c += 256) {
        if (counts[c] > 0) s += expf(row[c]);
    }
#pragma unroll
    for (int o = 32; o > 0; o >>= 1) s += __shfl_down(s, o);
    __shared__ float sw[4];
    int lane = threadIdx.x & 63, w = threadIdx.x >> 6;
    if (lane == 0) sw[w] = s;
    __syncthreads();
    if (threadIdx.x == 0) {
        float tot = sw[0] + sw[1] + sw[2] + sw[3];
        int t = labels[indexes[b]];
        float p = expf(row[t]) / (tot + EPSF);
        loss_b[b] = -logf(p + EPSF);
    }
}

// ---------- K6: deterministic final mean ----------
__global__ __launch_bounds__(256) void k_final(const float* __restrict__ loss_b,
                                               float* __restrict__ out) {
    float s = 0.f;
    for (int i = threadIdx.x; i < NB; i += 256) s += loss_b[i];
#pragma unroll
    for (int o = 32; o > 0; o >>= 1) s += __shfl_down(s, o);
    __shared__ float sw[4];
    int lane = threadIdx.x & 63, w = threadIdx.x >> 6;
    if (lane == 0) sw[w] = s;
    __syncthreads();
    if (threadIdx.x == 0) out[0] = (sw[0] + sw[1] + sw[2] + sw[3]) / (float)NB;
}

extern "C" void kernel_launch(void* const* d_in, const int* in_sizes, int n_in,
                              void* d_out, int out_size, void* d_ws, size_t ws_size,
                              hipStream_t stream) {
    const float* inputs   = (const float*)d_in[0];
    const int*   indexes  = (const int*)d_in[1];
    const float* features = (const float*)d_in[2];
    const int*   labels   = (const int*)d_in[3];
    float* out = (float*)d_out;

    // workspace layout
    float* G      = (float*)d_ws;                    // NC*ND   (8 MB)
    float* xn     = G + (size_t)NC * ND;             // NB*ND   (2 MB)
    float* avg    = xn + (size_t)NB * ND;            // NB*NC   (16 MB)
    float* loss_b = avg + (size_t)NB * NC;           // NB
    int*   counts = (int*)(loss_b + NB);             // NC

    hipMemsetAsync(G, 0, sizeof(float) * (size_t)NC * ND, stream);
    hipMemsetAsync(counts, 0, sizeof(int) * NC, stream);

    k_normalize<<<NB, 128, 0, stream>>>(inputs, xn);
    k_count<<<NM / 256, 256, 0, stream>>>(labels, counts);
    k_centroid<<<NM / RPB, 256, 0, stream>>>(features, labels, G);
    dim3 g(NC / 64, NB / 64);
    k_gemm<<<g, 256, 0, stream>>>(xn, G, counts, avg);
    k_loss<<<NB, 256, 0, stream>>>(avg, counts, indexes, labels, loss_b);
    k_final<<<1, 256, 0, stream>>>(loss_b, out);
}

// Round 2
// 155.085 us; speedup vs baseline: 2.1916x; 2.1916x over previous
//
#include <hip/hip_runtime.h>
#include <hip/hip_bf16.h>

#define NB 1024
#define ND 512
#define NM 65536
#define NC 4096

static constexpr float TEMP = 0.05f;
static constexpr float EPSF = 1e-6f;

// ---------- K1: row L2-normalize inputs (one 128-thread block per row) ----------
__global__ __launch_bounds__(128) void k_normalize(const float* __restrict__ in,
                                                   float* __restrict__ xn) {
    int b = blockIdx.x;
    const float4* row = reinterpret_cast<const float4*>(in + (size_t)b * ND);
    float4 v = row[threadIdx.x];
    float ss = v.x * v.x + v.y * v.y + v.z * v.z + v.w * v.w;
#pragma unroll
    for (int o = 32; o > 0; o >>= 1) ss += __shfl_down(ss, o);
    __shared__ float sw[2];
    int lane = threadIdx.x & 63, w = threadIdx.x >> 6;
    if (lane == 0) sw[w] = ss;
    __syncthreads();
    float inv = 1.0f / sqrtf(sw[0] + sw[1]);
    v.x *= inv; v.y *= inv; v.z *= inv; v.w *= inv;
    reinterpret_cast<float4*>(xn + (size_t)b * ND)[threadIdx.x] = v;
}

// ---------- K2: per-cluster member counts ----------
__global__ __launch_bounds__(256) void k_count(const int* __restrict__ labels,
                                               int* __restrict__ counts) {
    int m = blockIdx.x * 256 + threadIdx.x;
    if (m < NM) atomicAdd(&counts[labels[m]], 1);
}

// ---------- K2b: exclusive prefix scan over C=4096 counts (single block) ----------
__global__ __launch_bounds__(256) void k_scan(const int* __restrict__ counts,
                                              int* __restrict__ starts,
                                              int* __restrict__ cursor) {
    __shared__ int part[256];
    int t = threadIdx.x;
    int local[16];
    int base = t * 16;
    int s = 0;
#pragma unroll
    for (int i = 0; i < 16; ++i) { local[i] = counts[base + i]; s += local[i]; }
    part[t] = s;
    __syncthreads();
    // Hillis-Steele inclusive scan over 256 partials
    for (int off = 1; off < 256; off <<= 1) {
        int v = (t >= off) ? part[t - off] : 0;
        __syncthreads();
        part[t] += v;
        __syncthreads();
    }
    int excl = (t == 0) ? 0 : part[t - 1];
#pragma unroll
    for (int i = 0; i < 16; ++i) {
        starts[base + i] = excl;
        cursor[base + i] = excl;
        excl += local[i];
    }
}

// ---------- K2c: scatter member indices (counting sort, int atomics only) ----------
__global__ __launch_bounds__(256) void k_scatter(const int* __restrict__ labels,
                                                 int* __restrict__ cursor,
                                                 int* __restrict__ idx) {
    int m = blockIdx.x * 256 + threadIdx.x;
    int c = labels[m];
    int pos = atomicAdd(&cursor[c], 1);
    idx[pos] = m;
}

// ---------- K3: gather-sum features into cluster centroids (no float atomics) ----------
__global__ __launch_bounds__(128) void k_gather(const float* __restrict__ feats,
                                                const int* __restrict__ idx,
                                                const int* __restrict__ starts,
                                                const int* __restrict__ counts,
                                                float* __restrict__ G) {
    int c = blockIdx.x;
    int t = threadIdx.x;  // float4 column 0..127
    int s0 = starts[c];
    int n = counts[c];
    const float4* F = reinterpret_cast<const float4*>(feats);
    float4 acc = {0.f, 0.f, 0.f, 0.f};
    int j = 0;
    // 2-deep pipeline on the index load to break the idx->feat dependent chain
    int m_next = (n > 0) ? idx[s0] : 0;
    for (; j < n; ++j) {
        int m = m_next;
        if (j + 1 < n) m_next = idx[s0 + j + 1];
        float4 v = F[(size_t)m * 128 + t];
        acc.x += v.x; acc.y += v.y; acc.z += v.z; acc.w += v.w;
    }
    reinterpret_cast<float4*>(G)[(size_t)c * 128 + t] = acc;
}

// ---------- K4: avg[b][c] = (xn[b] . G[c]) / (TEMP * max(nums[c],1)) ----------
__global__ __launch_bounds__(256) void k_gemm(const float* __restrict__ A,
                                              const float* __restrict__ Bm,
                                              const int* __restrict__ counts,
                                              float* __restrict__ out) {
    __shared__ float As[16][65];
    __shared__ float Bs[16][65];
    const int bm = blockIdx.y * 64;  // over B (rows)
    const int bn = blockIdx.x * 64;  // over C (cols)
    const int tid = threadIdx.x;
    const int tx = tid & 15, ty = tid >> 4;
    const int lr = tid >> 2;          // 0..63 tile row to load
    const int lk = (tid & 3) << 2;    // 0,4,8,12 k offset
    float acc[4][4] = {};
    const float* Aptr = A + (size_t)(bm + lr) * ND + lk;
    const float* Bptr = Bm + (size_t)(bn + lr) * ND + lk;
    for (int k0 = 0; k0 < ND; k0 += 16) {
        float4 av = *reinterpret_cast<const float4*>(Aptr + k0);
        float4 bv = *reinterpret_cast<const float4*>(Bptr + k0);
        As[lk + 0][lr] = av.x; As[lk + 1][lr] = av.y;
        As[lk + 2][lr] = av.z; As[lk + 3][lr] = av.w;
        Bs[lk + 0][lr] = bv.x; Bs[lk + 1][lr] = bv.y;
        Bs[lk + 2][lr] = bv.z; Bs[lk + 3][lr] = bv.w;
        __syncthreads();
#pragma unroll
        for (int k = 0; k < 16; ++k) {
            float a0 = As[k][ty * 4 + 0], a1 = As[k][ty * 4 + 1];
            float a2 = As[k][ty * 4 + 2], a3 = As[k][ty * 4 + 3];
            float b0 = Bs[k][tx * 4 + 0], b1 = Bs[k][tx * 4 + 1];
            float b2 = Bs[k][tx * 4 + 2], b3 = Bs[k][tx * 4 + 3];
            acc[0][0] += a0 * b0; acc[0][1] += a0 * b1; acc[0][2] += a0 * b2; acc[0][3] += a0 * b3;
            acc[1][0] += a1 * b0; acc[1][1] += a1 * b1; acc[1][2] += a1 * b2; acc[1][3] += a1 * b3;
            acc[2][0] += a2 * b0; acc[2][1] += a2 * b1; acc[2][2] += a2 * b2; acc[2][3] += a2 * b3;
            acc[3][0] += a3 * b0; acc[3][1] += a3 * b1; acc[3][2] += a3 * b2; acc[3][3] += a3 * b3;
        }
        __syncthreads();
    }
    int c0 = bn + tx * 4;
    float i0 = 1.0f / (TEMP * (float)(counts[c0 + 0] > 0 ? counts[c0 + 0] : 1));
    float i1 = 1.0f / (TEMP * (float)(counts[c0 + 1] > 0 ? counts[c0 + 1] : 1));
    float i2 = 1.0f / (TEMP * (float)(counts[c0 + 2] > 0 ? counts[c0 + 2] : 1));
    float i3 = 1.0f / (TEMP * (float)(counts[c0 + 3] > 0 ? counts[c0 + 3] : 1));
#pragma unroll
    for (int i = 0; i < 4; ++i) {
        int rowb = bm + ty * 4 + i;
        float4 o;
        o.x = acc[i][0] * i0; o.y = acc[i][1] * i1;
        o.z = acc[i][2] * i2; o.w = acc[i][3] * i3;
        *reinterpret_cast<float4*>(out + (size_t)rowb * NC + c0) = o;
    }
}

// ---------- K5: per-sample masked softmax + NLL ----------
__global__ __launch_bounds__(256) void k_loss(const float* __restrict__ avg,
                                              const int* __restrict__ counts,
                                              const int* __restrict__ indexes,
                                              const int* __restrict__ labels,
                                              float* __restrict__ loss_b) {
    int b = blockIdx.x;
    const float* row = avg + (size_t)b * NC;
    float s = 0.f;
    for (int c = threadIdx.x; c < NC; c += 256) {
        if (counts[c] > 0) s += expf(row[c]);
    }
#pragma unroll
    for (int o = 32; o > 0; o >>= 1) s += __shfl_down(s, o);
    __shared__ float sw[4];
    int lane = threadIdx.x & 63, w = threadIdx.x >> 6;
    if (lane == 0) sw[w] = s;
    __syncthreads();
    if (threadIdx.x == 0) {
        float tot = sw[0] + sw[1] + sw[2] + sw[3];
        int t = labels[indexes[b]];
        float p = expf(row[t]) / (tot + EPSF);
        loss_b[b] = -logf(p + EPSF);
    }
}

// ---------- K6: deterministic final mean ----------
__global__ __launch_bounds__(256) void k_final(const float* __restrict__ loss_b,
                                               float* __restrict__ out) {
    float s = 0.f;
    for (int i = threadIdx.x; i < NB; i += 256) s += loss_b[i];
#pragma unroll
    for (int o = 32; o > 0; o >>= 1) s += __shfl_down(s, o);
    __shared__ float sw[4];
    int lane = threadIdx.x & 63, w = threadIdx.x >> 6;
    if (lane == 0) sw[w] = s;
    __syncthreads();
    if (threadIdx.x == 0) out[0] = (sw[0] + sw[1] + sw[2] + sw[3]) / (float)NB;
}

extern "C" void kernel_launch(void* const* d_in, const int* in_sizes, int n_in,
                              void* d_out, int out_size, void* d_ws, size_t ws_size,
                              hipStream_t stream) {
    const float* inputs   = (const float*)d_in[0];
    const int*   indexes  = (const int*)d_in[1];
    const float* features = (const float*)d_in[2];
    const int*   labels   = (const int*)d_in[3];
    float* out = (float*)d_out;

    // workspace layout
    float* G      = (float*)d_ws;                    // NC*ND   (8 MB)
    float* xn     = G + (size_t)NC * ND;             // NB*ND   (2 MB)
    float* avg    = xn + (size_t)NB * ND;            // NB*NC   (16 MB)
    float* loss_b = avg + (size_t)NB * NC;           // NB
    int*   counts = (int*)(loss_b + NB);             // NC
    int*   starts = counts + NC;                     // NC
    int*   cursor = starts + NC;                     // NC
    int*   idx    = cursor + NC;                     // NM (256 KB)

    hipMemsetAsync(counts, 0, sizeof(int) * NC, stream);

    k_normalize<<<NB, 128, 0, stream>>>(inputs, xn);
    k_count<<<NM / 256, 256, 0, stream>>>(labels, counts);
    k_scan<<<1, 256, 0, stream>>>(counts, starts, cursor);
    k_scatter<<<NM / 256, 256, 0, stream>>>(labels, cursor, idx);
    k_gather<<<NC, 128, 0, stream>>>(features, idx, starts, counts, G);
    dim3 g(NC / 64, NB / 64);
    k_gemm<<<g, 256, 0, stream>>>(xn, G, counts, avg);
    k_loss<<<NB, 256, 0, stream>>>(avg, counts, indexes, labels, loss_b);
    k_final<<<1, 256, 0, stream>>>(loss_b, out);
}

// Round 3
// 88.206 us; speedup vs baseline: 3.8533x; 1.7582x over previous
//
#include <hip/hip_runtime.h>
#include <hip/hip_bf16.h>

#define NB 1024
#define ND 512
#define NM 65536
#define NC 4096

static constexpr float TEMP = 0.05f;
static constexpr float EPSF = 1e-6f;

typedef __attribute__((ext_vector_type(8))) short short8v;   // 8 bf16 (4 VGPRs)
typedef __attribute__((ext_vector_type(16))) float f32x16;   // MFMA 32x32 accumulator

static __device__ __forceinline__ short f2bf(float f) {
    __hip_bfloat16 h = __float2bfloat16(f);
    return *reinterpret_cast<short*>(&h);
}

// ---------- K1: row L2-normalize inputs, emit bf16 (one 128-thread block per row) ----------
__global__ __launch_bounds__(128) void k_normalize(const float* __restrict__ in,
                                                   short* __restrict__ xnb) {
    int b = blockIdx.x;
    const float4* row = reinterpret_cast<const float4*>(in + (size_t)b * ND);
    float4 v = row[threadIdx.x];
    float ss = v.x * v.x + v.y * v.y + v.z * v.z + v.w * v.w;
#pragma unroll
    for (int o = 32; o > 0; o >>= 1) ss += __shfl_down(ss, o);
    __shared__ float sw[2];
    int lane = threadIdx.x & 63, w = threadIdx.x >> 6;
    if (lane == 0) sw[w] = ss;
    __syncthreads();
    float inv = 1.0f / sqrtf(sw[0] + sw[1]);
    short4 o;
    o.x = f2bf(v.x * inv); o.y = f2bf(v.y * inv);
    o.z = f2bf(v.z * inv); o.w = f2bf(v.w * inv);
    reinterpret_cast<short4*>(xnb + (size_t)b * ND)[threadIdx.x] = o;
}

// ---------- K2: per-cluster member counts ----------
__global__ __launch_bounds__(256) void k_count(const int* __restrict__ labels,
                                               int* __restrict__ counts) {
    int m = blockIdx.x * 256 + threadIdx.x;
    if (m < NM) atomicAdd(&counts[labels[m]], 1);
}

// ---------- K2b: exclusive prefix scan over C=4096 counts (single block) ----------
__global__ __launch_bounds__(256) void k_scan(const int* __restrict__ counts,
                                              int* __restrict__ starts,
                                              int* __restrict__ cursor) {
    __shared__ int part[256];
    int t = threadIdx.x;
    int local[16];
    int base = t * 16;
    int s = 0;
#pragma unroll
    for (int i = 0; i < 16; ++i) { local[i] = counts[base + i]; s += local[i]; }
    part[t] = s;
    __syncthreads();
    for (int off = 1; off < 256; off <<= 1) {
        int v = (t >= off) ? part[t - off] : 0;
        __syncthreads();
        part[t] += v;
        __syncthreads();
    }
    int excl = (t == 0) ? 0 : part[t - 1];
#pragma unroll
    for (int i = 0; i < 16; ++i) {
        starts[base + i] = excl;
        cursor[base + i] = excl;
        excl += local[i];
    }
}

// ---------- K2c: scatter member indices (counting sort, int atomics only) ----------
__global__ __launch_bounds__(256) void k_scatter(const int* __restrict__ labels,
                                                 int* __restrict__ cursor,
                                                 int* __restrict__ idx) {
    int m = blockIdx.x * 256 + threadIdx.x;
    int c = labels[m];
    int pos = atomicAdd(&cursor[c], 1);
    idx[pos] = m;
}

// ---------- K3: gather-sum features into bf16 cluster centroids ----------
__global__ __launch_bounds__(128) void k_gather(const float* __restrict__ feats,
                                                const int* __restrict__ idx,
                                                const int* __restrict__ starts,
                                                const int* __restrict__ counts,
                                                short* __restrict__ Gb) {
    int c = blockIdx.x;
    int t = threadIdx.x;  // float4 column 0..127
    int s0 = starts[c];
    int n = counts[c];
    const float4* F = reinterpret_cast<const float4*>(feats);
    float4 acc = {0.f, 0.f, 0.f, 0.f};
    int m_next = (n > 0) ? idx[s0] : 0;
    for (int j = 0; j < n; ++j) {
        int m = m_next;
        if (j + 1 < n) m_next = idx[s0 + j + 1];
        float4 v = F[(size_t)m * 128 + t];
        acc.x += v.x; acc.y += v.y; acc.z += v.z; acc.w += v.w;
    }
    short4 o;
    o.x = f2bf(acc.x); o.y = f2bf(acc.y); o.z = f2bf(acc.z); o.w = f2bf(acc.w);
    reinterpret_cast<short4*>(Gb + (size_t)c * ND)[t] = o;
}

// ---------- K4: MFMA GEMM  avg[b][c] = (xn[b].G[c]) / (TEMP*max(n_c,1)) ----------
// 128x128 block tile, 4 waves (2x2), wave = 64x64 via 2x2 v_mfma_f32_32x32x16_bf16.
// Operands read directly from global (L2-resident) — no LDS, no barriers.
__global__ __launch_bounds__(256) void k_gemm_mfma(const short* __restrict__ A,
                                                   const short* __restrict__ Bm,
                                                   const int* __restrict__ counts,
                                                   float* __restrict__ out) {
    const int tid = threadIdx.x;
    const int w = tid >> 6;
    const int lane = tid & 63;
    const int ln = lane & 31;
    const int kg = lane >> 5;
    const int row0 = blockIdx.y * 128 + (w >> 1) * 64;  // over B samples
    const int col0 = blockIdx.x * 128 + (w & 1) * 64;   // over clusters

    f32x16 acc00 = {}, acc01 = {}, acc10 = {}, acc11 = {};
    const short* pa0 = A + (size_t)(row0 + ln) * ND + kg * 8;
    const short* pa1 = pa0 + 32 * ND;
    const short* pb0 = Bm + (size_t)(col0 + ln) * ND + kg * 8;
    const short* pb1 = pb0 + 32 * ND;
#pragma unroll 4
    for (int k0 = 0; k0 < ND; k0 += 16) {
        short8v a0 = *reinterpret_cast<const short8v*>(pa0 + k0);
        short8v a1 = *reinterpret_cast<const short8v*>(pa1 + k0);
        short8v b0 = *reinterpret_cast<const short8v*>(pb0 + k0);
        short8v b1 = *reinterpret_cast<const short8v*>(pb1 + k0);
        acc00 = __builtin_amdgcn_mfma_f32_32x32x16_bf16(a0, b0, acc00, 0, 0, 0);
        acc01 = __builtin_amdgcn_mfma_f32_32x32x16_bf16(a0, b1, acc01, 0, 0, 0);
        acc10 = __builtin_amdgcn_mfma_f32_32x32x16_bf16(a1, b0, acc10, 0, 0, 0);
        acc11 = __builtin_amdgcn_mfma_f32_32x32x16_bf16(a1, b1, acc11, 0, 0, 0);
    }
    // C/D layout (m74/m101): col = lane&31, row = (reg&3) + 8*(reg>>2) + 4*(lane>>5)
    int colA = col0 + ln;
    int colB = col0 + 32 + ln;
    int nA = counts[colA], nB = counts[colB];
    float invA = 1.0f / (TEMP * (float)(nA > 0 ? nA : 1));
    float invB = 1.0f / (TEMP * (float)(nB > 0 ? nB : 1));
    int rbase = row0 + 4 * kg;
#pragma unroll
    for (int r = 0; r < 16; ++r) {
        int row = rbase + (r & 3) + 8 * (r >> 2);
        out[(size_t)row * NC + colA] = acc00[r] * invA;
        out[(size_t)row * NC + colB] = acc01[r] * invB;
        out[(size_t)(row + 32) * NC + colA] = acc10[r] * invA;
        out[(size_t)(row + 32) * NC + colB] = acc11[r] * invB;
    }
}

// ---------- K5: per-sample masked softmax + NLL ----------
__global__ __launch_bounds__(256) void k_loss(const float* __restrict__ avg,
                                              const int* __restrict__ counts,
                                              const int* __restrict__ indexes,
                                              const int* __restrict__ labels,
                                              float* __restrict__ loss_b) {
    int b = blockIdx.x;
    const float* row = avg + (size_t)b * NC;
    float s = 0.f;
    for (int c = threadIdx.x; c < NC; c += 256) {
        if (counts[c] > 0) s += expf(row[c]);
    }
#pragma unroll
    for (int o = 32; o > 0; o >>= 1) s += __shfl_down(s, o);
    __shared__ float sw[4];
    int lane = threadIdx.x & 63, w = threadIdx.x >> 6;
    if (lane == 0) sw[w] = s;
    __syncthreads();
    if (threadIdx.x == 0) {
        float tot = sw[0] + sw[1] + sw[2] + sw[3];
        int t = labels[indexes[b]];
        float p = expf(row[t]) / (tot + EPSF);
        loss_b[b] = -logf(p + EPSF);
    }
}

// ---------- K6: deterministic final mean ----------
__global__ __launch_bounds__(256) void k_final(const float* __restrict__ loss_b,
                                               float* __restrict__ out) {
    float s = 0.f;
    for (int i = threadIdx.x; i < NB; i += 256) s += loss_b[i];
#pragma unroll
    for (int o = 32; o > 0; o >>= 1) s += __shfl_down(s, o);
    __shared__ float sw[4];
    int lane = threadIdx.x & 63, w = threadIdx.x >> 6;
    if (lane == 0) sw[w] = s;
    __syncthreads();
    if (threadIdx.x == 0) out[0] = (sw[0] + sw[1] + sw[2] + sw[3]) / (float)NB;
}

extern "C" void kernel_launch(void* const* d_in, const int* in_sizes, int n_in,
                              void* d_out, int out_size, void* d_ws, size_t ws_size,
                              hipStream_t stream) {
    const float* inputs   = (const float*)d_in[0];
    const int*   indexes  = (const int*)d_in[1];
    const float* features = (const float*)d_in[2];
    const int*   labels   = (const int*)d_in[3];
    float* out = (float*)d_out;

    // workspace layout
    float* avg    = (float*)d_ws;                    // NB*NC f32 (16 MB)
    short* Gb     = (short*)(avg + (size_t)NB * NC); // NC*ND bf16 (4 MB)
    short* xnb    = Gb + (size_t)NC * ND;            // NB*ND bf16 (1 MB)
    float* loss_b = (float*)(xnb + (size_t)NB * ND); // NB
    int*   counts = (int*)(loss_b + NB);             // NC
    int*   starts = counts + NC;                     // NC
    int*   cursor = starts + NC;                     // NC
    int*   idx    = cursor + NC;                     // NM (256 KB)

    hipMemsetAsync(counts, 0, sizeof(int) * NC, stream);

    k_normalize<<<NB, 128, 0, stream>>>(inputs, xnb);
    k_count<<<NM / 256, 256, 0, stream>>>(labels, counts);
    k_scan<<<1, 256, 0, stream>>>(counts, starts, cursor);
    k_scatter<<<NM / 256, 256, 0, stream>>>(labels, cursor, idx);
    k_gather<<<NC, 128, 0, stream>>>(features, idx, starts, counts, Gb);
    dim3 g(NC / 128, NB / 128);
    k_gemm_mfma<<<g, 256, 0, stream>>>(xnb, Gb, counts, avg);
    k_loss<<<NB, 256, 0, stream>>>(avg, counts, indexes, labels, loss_b);
    k_final<<<1, 256, 0, stream>>>(loss_b, out);
}

// Round 4
// 86.493 us; speedup vs baseline: 3.9296x; 1.0198x over previous
//
#include <hip/hip_runtime.h>
#include <hip/hip_bf16.h>

#define NB 1024
#define ND 512
#define NM 65536
#define NC 4096

static constexpr float TEMP = 0.05f;
static constexpr float EPSF = 1e-6f;

typedef __attribute__((ext_vector_type(8))) short short8v;   // 8 bf16 (4 VGPRs)
typedef __attribute__((ext_vector_type(16))) float f32x16;   // MFMA 32x32 accumulator

static __device__ __forceinline__ short f2bf(float f) {
    __hip_bfloat16 h = __float2bfloat16(f);
    return *reinterpret_cast<short*>(&h);
}

// ---------- K0: zero counts/denom, precompute tgt[b] = labels[indexes[b]] ----------
__global__ __launch_bounds__(256) void k_zero_tgt(const int* __restrict__ indexes,
                                                  const int* __restrict__ labels,
                                                  int* __restrict__ counts,
                                                  float* __restrict__ denom,
                                                  int* __restrict__ tgt) {
    int i = blockIdx.x * 256 + threadIdx.x;
    if (i < NC) counts[i] = 0;
    if (i < NB) {
        denom[i] = 0.f;
        tgt[i] = labels[indexes[i]];
    }
}

// ---------- K1: row L2-normalize inputs, emit bf16 ----------
__global__ __launch_bounds__(128) void k_normalize(const float* __restrict__ in,
                                                   short* __restrict__ xnb) {
    int b = blockIdx.x;
    const float4* row = reinterpret_cast<const float4*>(in + (size_t)b * ND);
    float4 v = row[threadIdx.x];
    float ss = v.x * v.x + v.y * v.y + v.z * v.z + v.w * v.w;
#pragma unroll
    for (int o = 32; o > 0; o >>= 1) ss += __shfl_down(ss, o);
    __shared__ float sw[2];
    int lane = threadIdx.x & 63, w = threadIdx.x >> 6;
    if (lane == 0) sw[w] = ss;
    __syncthreads();
    float inv = 1.0f / sqrtf(sw[0] + sw[1]);
    short4 o;
    o.x = f2bf(v.x * inv); o.y = f2bf(v.y * inv);
    o.z = f2bf(v.z * inv); o.w = f2bf(v.w * inv);
    reinterpret_cast<short4*>(xnb + (size_t)b * ND)[threadIdx.x] = o;
}

// ---------- K2: per-cluster member counts ----------
__global__ __launch_bounds__(256) void k_count(const int* __restrict__ labels,
                                               int* __restrict__ counts) {
    int m = blockIdx.x * 256 + threadIdx.x;
    if (m < NM) atomicAdd(&counts[labels[m]], 1);
}

// ---------- K2b: exclusive prefix scan over C=4096 counts (single block) ----------
__global__ __launch_bounds__(256) void k_scan(const int* __restrict__ counts,
                                              int* __restrict__ starts,
                                              int* __restrict__ cursor) {
    __shared__ int part[256];
    int t = threadIdx.x;
    int local[16];
    int base = t * 16;
    int s = 0;
#pragma unroll
    for (int i = 0; i < 16; ++i) { local[i] = counts[base + i]; s += local[i]; }
    part[t] = s;
    __syncthreads();
    for (int off = 1; off < 256; off <<= 1) {
        int v = (t >= off) ? part[t - off] : 0;
        __syncthreads();
        part[t] += v;
        __syncthreads();
    }
    int excl = (t == 0) ? 0 : part[t - 1];
#pragma unroll
    for (int i = 0; i < 16; ++i) {
        starts[base + i] = excl;
        cursor[base + i] = excl;
        excl += local[i];
    }
}

// ---------- K2c: scatter member indices (counting sort, int atomics only) ----------
__global__ __launch_bounds__(256) void k_scatter(const int* __restrict__ labels,
                                                 int* __restrict__ cursor,
                                                 int* __restrict__ idx) {
    int m = blockIdx.x * 256 + threadIdx.x;
    int c = labels[m];
    int pos = atomicAdd(&cursor[c], 1);
    idx[pos] = m;
}

// ---------- K3: gather-sum features into bf16 cluster centroids ----------
__global__ __launch_bounds__(128) void k_gather(const float* __restrict__ feats,
                                                const int* __restrict__ idx,
                                                const int* __restrict__ starts,
                                                const int* __restrict__ counts,
                                                short* __restrict__ Gb) {
    int c = blockIdx.x;
    int t = threadIdx.x;  // float4 column 0..127
    int s0 = starts[c];
    int n = counts[c];
    const float4* F = reinterpret_cast<const float4*>(feats);
    float4 a0 = {0.f, 0.f, 0.f, 0.f};
    float4 a1 = {0.f, 0.f, 0.f, 0.f};
    int j = 0;
    for (; j + 1 < n; j += 2) {
        int m0 = idx[s0 + j];
        int m1 = idx[s0 + j + 1];
        float4 v0 = F[(size_t)m0 * 128 + t];
        float4 v1 = F[(size_t)m1 * 128 + t];
        a0.x += v0.x; a0.y += v0.y; a0.z += v0.z; a0.w += v0.w;
        a1.x += v1.x; a1.y += v1.y; a1.z += v1.z; a1.w += v1.w;
    }
    if (j < n) {
        int m0 = idx[s0 + j];
        float4 v0 = F[(size_t)m0 * 128 + t];
        a0.x += v0.x; a0.y += v0.y; a0.z += v0.z; a0.w += v0.w;
    }
    short4 o;
    o.x = f2bf(a0.x + a1.x); o.y = f2bf(a0.y + a1.y);
    o.z = f2bf(a0.z + a1.z); o.w = f2bf(a0.w + a1.w);
    reinterpret_cast<short4*>(Gb + (size_t)c * ND)[t] = o;
}

// ---------- K4: MFMA GEMM + fused masked-softmax partial reduction ----------
// 128x128 block tile, 4 waves (2x2), wave = 64x64 via 2x2 v_mfma_f32_32x32x16_bf16.
// Epilogue: per-row sum of exp(logit)*mask -> atomicAdd denom[row];
//           target logit -> numer[row] (unique writer).
__global__ __launch_bounds__(256) void k_gemm_mfma(const short* __restrict__ A,
                                                   const short* __restrict__ Bm,
                                                   const int* __restrict__ counts,
                                                   const int* __restrict__ tgt,
                                                   float* __restrict__ denom,
                                                   float* __restrict__ numer) {
    const int tid = threadIdx.x;
    const int w = tid >> 6;
    const int lane = tid & 63;
    const int ln = lane & 31;
    const int kg = lane >> 5;
    const int row0 = blockIdx.y * 128 + (w >> 1) * 64;  // over B samples
    const int col0 = blockIdx.x * 128 + (w & 1) * 64;   // over clusters

    f32x16 acc00 = {}, acc01 = {}, acc10 = {}, acc11 = {};
    const short* pa0 = A + (size_t)(row0 + ln) * ND + kg * 8;
    const short* pa1 = pa0 + 32 * ND;
    const short* pb0 = Bm + (size_t)(col0 + ln) * ND + kg * 8;
    const short* pb1 = pb0 + 32 * ND;
#pragma unroll 4
    for (int k0 = 0; k0 < ND; k0 += 16) {
        short8v a0 = *reinterpret_cast<const short8v*>(pa0 + k0);
        short8v a1 = *reinterpret_cast<const short8v*>(pa1 + k0);
        short8v b0 = *reinterpret_cast<const short8v*>(pb0 + k0);
        short8v b1 = *reinterpret_cast<const short8v*>(pb1 + k0);
        acc00 = __builtin_amdgcn_mfma_f32_32x32x16_bf16(a0, b0, acc00, 0, 0, 0);
        acc01 = __builtin_amdgcn_mfma_f32_32x32x16_bf16(a0, b1, acc01, 0, 0, 0);
        acc10 = __builtin_amdgcn_mfma_f32_32x32x16_bf16(a1, b0, acc10, 0, 0, 0);
        acc11 = __builtin_amdgcn_mfma_f32_32x32x16_bf16(a1, b1, acc11, 0, 0, 0);
    }
    // C/D layout (m74/m101): col = lane&31, row = (reg&3) + 8*(reg>>2) + 4*(lane>>5)
    int colA = col0 + ln;
    int colB = colA + 32;
    int nA = counts[colA], nB = counts[colB];
    float invA = 1.0f / (TEMP * (float)(nA > 0 ? nA : 1));
    float invB = 1.0f / (TEMP * (float)(nB > 0 ? nB : 1));
    float mA = (nA > 0) ? 1.f : 0.f;
    float mB = (nB > 0) ? 1.f : 0.f;
    int rbase = row0 + 4 * kg;
#pragma unroll
    for (int r = 0; r < 16; ++r) {
        int row = rbase + (r & 3) + 8 * (r >> 2);
        int rowH = row + 32;
        float v00 = acc00[r] * invA, v01 = acc01[r] * invB;
        float v10 = acc10[r] * invA, v11 = acc11[r] * invB;
        int t0 = tgt[row], t1 = tgt[rowH];
        if (t0 == colA) numer[row] = v00;
        if (t0 == colB) numer[row] = v01;
        if (t1 == colA) numer[rowH] = v10;
        if (t1 == colB) numer[rowH] = v11;
        float s0 = mA * __expf(v00) + mB * __expf(v01);
        float s1 = mA * __expf(v10) + mB * __expf(v11);
#pragma unroll
        for (int m = 1; m < 32; m <<= 1) {
            s0 += __shfl_xor(s0, m);
            s1 += __shfl_xor(s1, m);
        }
        if (ln == 0) {
            atomicAdd(&denom[row], s0);
            atomicAdd(&denom[rowH], s1);
        }
    }
}

// ---------- K5: final loss (deterministic single-block mean) ----------
__global__ __launch_bounds__(256) void k_final(const float* __restrict__ numer,
                                               const float* __restrict__ denom,
                                               float* __restrict__ out) {
    float s = 0.f;
    for (int i = threadIdx.x; i < NB; i += 256) {
        float p = __expf(numer[i]) / (denom[i] + EPSF);
        s += -logf(p + EPSF);
    }
#pragma unroll
    for (int o = 32; o > 0; o >>= 1) s += __shfl_down(s, o);
    __shared__ float sw[4];
    int lane = threadIdx.x & 63, w = threadIdx.x >> 6;
    if (lane == 0) sw[w] = s;
    __syncthreads();
    if (threadIdx.x == 0) out[0] = (sw[0] + sw[1] + sw[2] + sw[3]) / (float)NB;
}

extern "C" void kernel_launch(void* const* d_in, const int* in_sizes, int n_in,
                              void* d_out, int out_size, void* d_ws, size_t ws_size,
                              hipStream_t stream) {
    const float* inputs   = (const float*)d_in[0];
    const int*   indexes  = (const int*)d_in[1];
    const float* features = (const float*)d_in[2];
    const int*   labels   = (const int*)d_in[3];
    float* out = (float*)d_out;

    // workspace layout (all written before read each call; no memsets)
    short* Gb     = (short*)d_ws;                    // NC*ND bf16 (4 MB)
    short* xnb    = Gb + (size_t)NC * ND;            // NB*ND bf16 (1 MB)
    float* denom  = (float*)(xnb + (size_t)NB * ND); // NB
    float* numer  = denom + NB;                      // NB
    int*   tgt    = (int*)(numer + NB);              // NB
    int*   counts = tgt + NB;                        // NC
    int*   starts = counts + NC;                     // NC
    int*   cursor = starts + NC;                     // NC
    int*   idx    = cursor + NC;                     // NM (256 KB)

    k_zero_tgt<<<16, 256, 0, stream>>>(indexes, labels, counts, denom, tgt);
    k_normalize<<<NB, 128, 0, stream>>>(inputs, xnb);
    k_count<<<NM / 256, 256, 0, stream>>>(labels, counts);
    k_scan<<<1, 256, 0, stream>>>(counts, starts, cursor);
    k_scatter<<<NM / 256, 256, 0, stream>>>(labels, cursor, idx);
    k_gather<<<NC, 128, 0, stream>>>(features, idx, starts, counts, Gb);
    dim3 g(NC / 128, NB / 128);
    k_gemm_mfma<<<g, 256, 0, stream>>>(xnb, Gb, counts, tgt, denom, numer);
    k_final<<<1, 256, 0, stream>>>(numer, denom, out);
}